// Round 1
// 495.674 us; speedup vs baseline: 1.0950x; 1.0950x over previous
//
#include <hip/hip_runtime.h>
#include <math.h>

#define HWp 16384
#define CH 64
#define KC 8
#define WSTRIDE 136

typedef __attribute__((ext_vector_type(8))) short bf16x8;
typedef __attribute__((ext_vector_type(4))) float f32x4;

#define MFMA(a, b, c) __builtin_amdgcn_mfma_f32_16x16x32_bf16(a, b, c, 0, 0, 0)

__device__ __forceinline__ short f2bf(float f) {
  unsigned u = __float_as_uint(f);
  u += 0x7FFFu + ((u >> 16) & 1u);   // round-to-nearest-even
  return (short)(u >> 16);
}
__device__ __forceinline__ float bf2f(short s) {
  return __uint_as_float(((unsigned)(unsigned short)s) << 16);
}

// B-fragment: B[k=c][n=e] = W[e][c], lane l reads 8 contiguous c at e = nrow
__device__ __forceinline__ bf16x8 ldB(const short* __restrict__ W, int nrow, int c0) {
  return *(const bf16x8*)(W + nrow * WSTRIDE + c0);
}
// A-fragment from bf16 row-major z: 16B contiguous
__device__ __forceinline__ bf16x8 ldA_z(const short* __restrict__ zrow, int c0) {
  return *(const bf16x8*)(zrow + c0);
}

// ---- XOR-swizzled bf16 LDS tile: [p][64ch], 16B chunk index = (c>>3)^(p&7) ----
// Fragment read: one ds_read_b128, bank-uniform across the wave.
__device__ __forceinline__ bf16x8 ldT(const short* tile, int p, int c0) {
  return *(const bf16x8*)(tile + p * 64 + ((((c0 >> 3) ^ p) & 7) << 3));
}

// Stage one 64ch x 64px fp32 channel-major tile -> swizzled bf16 [64px][64ch] LDS tile.
// Thread t owns channels (2*(t>>3), 2*(t>>3)+1) x pixels 8*(t&7)..+7.
// Global reads: coalesced float4 (8 x 128B runs per wave-instr). LDS writes: packed dwords.
__device__ __forceinline__ void stage_tile(short* dst, const float* __restrict__ src, int t) {
  const int ch = (t >> 3) << 1;
  const int pg = (t & 7) << 3;
  const float* r0 = src + (size_t)ch * HWp + pg;
  const float* r1 = r0 + HWp;
  f32x4 a0 = *(const f32x4*)r0;
  f32x4 a1 = *(const f32x4*)(r0 + 4);
  f32x4 b0 = *(const f32x4*)r1;
  f32x4 b1 = *(const f32x4*)(r1 + 4);
  const int cb = (ch >> 3) & 7;
  const int cs = ch & 7;  // even -> dword-aligned short slot
#pragma unroll
  for (int j = 0; j < 8; ++j) {
    float fa = (j < 4) ? a0[j & 3] : a1[j & 3];
    float fb = (j < 4) ? b0[j & 3] : b1[j & 3];
    unsigned dw = (unsigned)(unsigned short)f2bf(fa) |
                  ((unsigned)(unsigned short)f2bf(fb) << 16);
    // p = pg + j, p&7 == j (pg multiple of 8)
    *(unsigned*)(dst + (pg + j) * 64 + ((cb ^ j) << 3) + cs) = dw;
  }
}

// Stage 64ch x 8px query tile (fp32 channel-major) -> swizzled bf16 [8px][64ch].
__device__ __forceinline__ void stage_q(short* dst, const float* __restrict__ src, int t) {
  const int c = t >> 2;
  const int p2 = (t & 3) << 1;
  float x0 = src[(size_t)c * HWp + p2];
  float x1 = src[(size_t)c * HWp + p2 + 1];
  const int cb = (c >> 3) & 7;
  const int cs = c & 7;
  dst[p2 * 64 + ((cb ^ (p2 & 7)) << 3) + cs] = f2bf(x0);
  dst[(p2 + 1) * 64 + ((cb ^ ((p2 + 1) & 7)) << 3) + cs] = f2bf(x1);
}

// Fold MHA in-projection into q/k/v linears; store W^T[e][c] bf16 (stride 136) + biases fp32.
__global__ void setup_weights(const float* __restrict__ q1w, const float* __restrict__ q1b,
                              const float* __restrict__ k1w, const float* __restrict__ k1b,
                              const float* __restrict__ v1w, const float* __restrict__ v1b,
                              const float* __restrict__ q2w, const float* __restrict__ q2b,
                              const float* __restrict__ k2w, const float* __restrict__ k2b,
                              const float* __restrict__ v2w, const float* __restrict__ v2b,
                              const float* __restrict__ ipw, const float* __restrict__ ipb,
                              const float* __restrict__ ow, short* __restrict__ Wt,
                              float* __restrict__ Bc) {
  int id = blockIdx.y;
  int idx = blockIdx.x * 256 + threadIdx.x;
  if (id == 6) {  // out_w: B[k=d][n=e] = ow[e][d] -> store row-major [e][d] bf16
    if (idx < 4096) {
      int e = idx >> 6, d = idx & 63;
      Wt[(6 * 64 + e) * WSTRIDE + d] = f2bf(ow[e * 64 + d]);
    }
    return;
  }
  const float* lw; const float* lb; int K, off;
  switch (id) {
    case 0:  lw = q1w; lb = q1b; K = 66;  off = 0;   break;
    case 1:  lw = k1w; lb = k1b; K = 66;  off = 64;  break;
    case 2:  lw = v1w; lb = v1b; K = 64;  off = 128; break;
    case 3:  lw = q2w; lb = q2b; K = 130; off = 0;   break;
    case 4:  lw = k2w; lb = k2b; K = 130; off = 64;  break;
    default: lw = v2w; lb = v2b; K = 128; off = 128; break;
  }
  if (idx < K * 64) {
    int c = idx >> 6, e = idx & 63;
    float s = 0.f;
    for (int f = 0; f < 64; ++f) s += ipw[(off + e) * 64 + f] * lw[f * K + c];
    Wt[(id * 64 + e) * WSTRIDE + c] = f2bf(s);
  } else if (idx < K * 64 + 64) {
    int e = idx - K * 64;
    float s = ipb[off + e];
    for (int f = 0; f < 64; ++f) s += ipw[(off + e) * 64 + f] * lb[f];
    Bc[id * 64 + e] = s;
  }
}

// ---------------- Stage 1 ----------------
__global__ __launch_bounds__(256) void stage1(const float* __restrict__ HFs,
                                              const float* __restrict__ HFc,
                                              const float* __restrict__ Zc,
                                              const short* __restrict__ Wt,
                                              const float* __restrict__ Bc,
                                              const float* __restrict__ outb,
                                              short* __restrict__ zb) {
  const int t = threadIdx.x;
  const int wv = t >> 6, l = t & 63;
  const int tile = blockIdx.x;
  const int b = tile >> 11;
  const int p0 = (tile & 2047) << 3;
  const int m0 = p0 << 3;
  const int k0 = m0 >> 14;
  const int poff = m0 & (HWp - 1);

  __shared__ float KV[64 * 77];
  __shared__ float QH[8 * 68];
  __shared__ float AO[8 * 68];
  __shared__ float ATT[256];
  __shared__ __align__(16) short KT[64 * 64];
  __shared__ __align__(16) short VT[64 * 64];
  __shared__ __align__(16) short QT[8 * 64];

  const int am = l & 15, kg = l >> 4, n = l & 15;
  const int row0 = wv * 16;

  const short* Wq = Wt + 0 * 64 * WSTRIDE;
  const short* Wk = Wt + 1 * 64 * WSTRIDE;
  const short* Wv = Wt + 2 * 64 * WSTRIDE;
  const short* Wo = Wt + 6 * 64 * WSTRIDE;
  const float* BQ = Bc + 0 * 64;
  const float* BK = Bc + 1 * 64;
  const float* BV = Bc + 2 * 64;

  const float* baseKc = HFc + ((size_t)(b * KC + k0) * CH) * HWp + poff;
  const float* baseZc = Zc + ((size_t)(b * KC + k0) * CH) * HWp + poff;
  const float* baseQ = HFs + (size_t)b * CH * HWp;
  const float inv127 = 1.f / 127.f;

  // ---- coalesced staging: global fp32 (channel-major) -> swizzled bf16 LDS (pixel-major) ----
  stage_tile(KT, baseKc, t);
  stage_tile(VT, baseZc, t);
  stage_q(QT, baseQ + p0, t);

  // ---- K-GEMM (64x64x64 + coords) & Q-GEMM (col-tile per wave) ----
  f32x4 kacc[4];
#pragma unroll
  for (int ct = 0; ct < 4; ++ct) {
    int col = ct * 16 + n;
    float bk = BK[col];
    float wi = bf2f(Wk[col * WSTRIDE + 64]);
    float wj = bf2f(Wk[col * WSTRIDE + 65]);
#pragma unroll
    for (int r = 0; r < 4; ++r) {
      int pp = poff + row0 + kg * 4 + r;
      kacc[ct][r] = bk + (float)(pp >> 7) * inv127 * wi + (float)(pp & 127) * inv127 * wj;
    }
  }
  f32x4 qacc;
  {
    int colq = wv * 16 + n;
    float bq = BQ[colq];
    float wi = bf2f(Wq[colq * WSTRIDE + 64]);
    float wj = bf2f(Wq[colq * WSTRIDE + 65]);
#pragma unroll
    for (int r = 0; r < 4; ++r) {
      int p = p0 + ((kg * 4 + r) & 7);
      qacc[r] = bq + (float)(p >> 7) * inv127 * wi + (float)(p & 127) * inv127 * wj;
    }
  }
  __syncthreads();
#pragma unroll
  for (int ks = 0; ks < 2; ++ks) {
    int c0 = ks * 32 + kg * 8;
    bf16x8 a = ldT(KT, row0 + am, c0);
#pragma unroll
    for (int ct = 0; ct < 4; ++ct) kacc[ct] = MFMA(a, ldB(Wk, ct * 16 + n, c0), kacc[ct]);
    bf16x8 aq = ldT(QT, am & 7, c0);
    qacc = MFMA(aq, ldB(Wq, wv * 16 + n, c0), qacc);
  }
#pragma unroll
  for (int ct = 0; ct < 4; ++ct)
#pragma unroll
    for (int r = 0; r < 4; ++r)
      KV[(row0 + kg * 4 + r) * 77 + ct * 16 + n] = kacc[ct][r];
#pragma unroll
  for (int r = 0; r < 4; ++r) {
    int m = kg * 4 + r;
    if (m < 8) QH[m * 68 + wv * 16 + n] = qacc[r];
  }
  __syncthreads();

  // ---- scores: thread = (pixel, head, key), softmax over 8 lanes ----
  {
    int p = t >> 5, k = t & 7, h = (t >> 3) & 3;
    const float* qrow = &QH[p * 68 + h * 16];
    const float* krow = &KV[(p * 8 + k) * 77 + h * 16];
    float s = 0.f;
#pragma unroll
    for (int d = 0; d < 16; ++d) s += qrow[d] * krow[d];
    s *= 0.25f;
    float mx = s;
    mx = fmaxf(mx, __shfl_xor(mx, 1));
    mx = fmaxf(mx, __shfl_xor(mx, 2));
    mx = fmaxf(mx, __shfl_xor(mx, 4));
    float e = __expf(s - mx);
    float sum = e;
    sum += __shfl_xor(sum, 1);
    sum += __shfl_xor(sum, 2);
    sum += __shfl_xor(sum, 4);
    ATT[t] = e / sum;
  }
  __syncthreads();

  // ---- V-GEMM (overwrites KV buffer) ----
  f32x4 vacc[4];
#pragma unroll
  for (int ct = 0; ct < 4; ++ct) {
    float bv = BV[ct * 16 + n];
#pragma unroll
    for (int r = 0; r < 4; ++r) vacc[ct][r] = bv;
  }
#pragma unroll
  for (int ks = 0; ks < 2; ++ks) {
    int c0 = ks * 32 + kg * 8;
    bf16x8 a = ldT(VT, row0 + am, c0);
#pragma unroll
    for (int ct = 0; ct < 4; ++ct) vacc[ct] = MFMA(a, ldB(Wv, ct * 16 + n, c0), vacc[ct]);
  }
#pragma unroll
  for (int ct = 0; ct < 4; ++ct)
#pragma unroll
    for (int r = 0; r < 4; ++r)
      KV[(row0 + kg * 4 + r) * 77 + ct * 16 + n] = vacc[ct][r];
  __syncthreads();

  // ---- attn @ V: thread = (pixel, head, d-pair) ----
  {
    int p = t >> 5, dp = t & 7, h = (t >> 3) & 3;
    int d0 = h * 16 + dp * 2;
    float o0 = 0.f, o1 = 0.f;
#pragma unroll
    for (int k = 0; k < 8; ++k) {
      float a = ATT[(t & ~7) + k];
      const float* vrow = &KV[(p * 8 + k) * 77 + d0];
      o0 += a * vrow[0];
      o1 += a * vrow[1];
    }
    AO[p * 68 + d0] = o0;
    AO[p * 68 + d0 + 1] = o1;
  }
  __syncthreads();

  // ---- out-proj -> z (bf16 in ws) ----
  {
    int colo = wv * 16 + n;
    f32x4 oacc;
    float bo = outb[colo];
#pragma unroll
    for (int r = 0; r < 4; ++r) oacc[r] = bo;
#pragma unroll
    for (int ks = 0; ks < 2; ++ks) {
      int c0 = ks * 32 + kg * 8;
      bf16x8 a;
#pragma unroll
      for (int j = 0; j < 8; ++j) a[j] = f2bf(AO[(am & 7) * 68 + c0 + j]);
      oacc = MFMA(a, ldB(Wo, colo, c0), oacc);
    }
#pragma unroll
    for (int r = 0; r < 4; ++r) {
      int m = kg * 4 + r;
      if (m < 8) zb[((size_t)(b * HWp + p0 + m)) * 64 + colo] = f2bf(oacc[r]);
    }
  }
}

// ---------------- Stage 2 ----------------
__global__ __launch_bounds__(256) void stage2(const float* __restrict__ HFs,
                                              const float* __restrict__ HFc,
                                              const float* __restrict__ Zc,
                                              const short* __restrict__ Wt,
                                              const float* __restrict__ Bc,
                                              const float* __restrict__ outb,
                                              const short* __restrict__ zb,
                                              float* __restrict__ out) {
  const int t = threadIdx.x;
  const int wv = t >> 6, l = t & 63;
  const int tile = blockIdx.x;
  const int b = tile >> 11;
  const int p0 = (tile & 2047) << 3;
  const int m0 = p0 << 3;
  const int k0 = m0 >> 14;
  const int poff = m0 & (HWp - 1);

  __shared__ float KV[64 * 77];
  __shared__ float QH[8 * 68];
  __shared__ float AO[8 * 68];
  __shared__ float ATT[256];
  __shared__ __align__(16) short KT[64 * 64];
  __shared__ __align__(16) short VT[64 * 64];
  __shared__ __align__(16) short QT[8 * 64];

  const int am = l & 15, kg = l >> 4, n = l & 15;
  const int row0 = wv * 16;

  const short* Wq = Wt + 3 * 64 * WSTRIDE;
  const short* Wk = Wt + 4 * 64 * WSTRIDE;
  const short* Wv = Wt + 5 * 64 * WSTRIDE;
  const short* Wo = Wt + 6 * 64 * WSTRIDE;
  const float* BQ = Bc + 3 * 64;
  const float* BK = Bc + 4 * 64;
  const float* BV = Bc + 5 * 64;

  const float* baseKc = HFc + ((size_t)(b * KC + k0) * CH) * HWp + poff;
  const float* baseZc = Zc + ((size_t)(b * KC + k0) * CH) * HWp + poff;
  const float* baseQ = HFs + (size_t)b * CH * HWp;
  const short* zK = zb + ((size_t)(b * HWp + poff + row0 + am)) * 64;  // key-row z
  const short* zQ = zb + ((size_t)(b * HWp + p0 + (am & 7))) * 64;     // query z
  const float inv127 = 1.f / 127.f;

  // ---- coalesced staging ----
  stage_tile(KT, baseKc, t);
  stage_tile(VT, baseZc, t);
  stage_q(QT, baseQ + p0, t);

  // ---- K-GEMM: [Kc | z | coords] @ Wk2c ----
  f32x4 kacc[4];
#pragma unroll
  for (int ct = 0; ct < 4; ++ct) {
    int col = ct * 16 + n;
    float bk = BK[col];
    float wi = bf2f(Wk[col * WSTRIDE + 128]);
    float wj = bf2f(Wk[col * WSTRIDE + 129]);
#pragma unroll
    for (int r = 0; r < 4; ++r) {
      int pp = poff + row0 + kg * 4 + r;
      kacc[ct][r] = bk + (float)(pp >> 7) * inv127 * wi + (float)(pp & 127) * inv127 * wj;
    }
  }
  f32x4 qacc;
  {
    int colq = wv * 16 + n;
    float bq = BQ[colq];
    float wi = bf2f(Wq[colq * WSTRIDE + 128]);
    float wj = bf2f(Wq[colq * WSTRIDE + 129]);
#pragma unroll
    for (int r = 0; r < 4; ++r) {
      int p = p0 + ((kg * 4 + r) & 7);
      qacc[r] = bq + (float)(p >> 7) * inv127 * wi + (float)(p & 127) * inv127 * wj;
    }
  }
  __syncthreads();
#pragma unroll
  for (int ks = 0; ks < 4; ++ks) {
    int c0 = ks * 32 + kg * 8;
    bf16x8 a = (ks < 2) ? ldT(KT, row0 + am, c0) : ldA_z(zK, c0 - 64);
#pragma unroll
    for (int ct = 0; ct < 4; ++ct) kacc[ct] = MFMA(a, ldB(Wk, ct * 16 + n, c0), kacc[ct]);
    bf16x8 aq = (ks < 2) ? ldT(QT, am & 7, c0) : ldA_z(zQ, c0 - 64);
    qacc = MFMA(aq, ldB(Wq, wv * 16 + n, c0), qacc);
  }
#pragma unroll
  for (int ct = 0; ct < 4; ++ct)
#pragma unroll
    for (int r = 0; r < 4; ++r)
      KV[(row0 + kg * 4 + r) * 77 + ct * 16 + n] = kacc[ct][r];
#pragma unroll
  for (int r = 0; r < 4; ++r) {
    int m = kg * 4 + r;
    if (m < 8) QH[m * 68 + wv * 16 + n] = qacc[r];
  }
  __syncthreads();

  // ---- scores ----
  {
    int p = t >> 5, k = t & 7, h = (t >> 3) & 3;
    const float* qrow = &QH[p * 68 + h * 16];
    const float* krow = &KV[(p * 8 + k) * 77 + h * 16];
    float s = 0.f;
#pragma unroll
    for (int d = 0; d < 16; ++d) s += qrow[d] * krow[d];
    s *= 0.25f;
    float mx = s;
    mx = fmaxf(mx, __shfl_xor(mx, 1));
    mx = fmaxf(mx, __shfl_xor(mx, 2));
    mx = fmaxf(mx, __shfl_xor(mx, 4));
    float e = __expf(s - mx);
    float sum = e;
    sum += __shfl_xor(sum, 1);
    sum += __shfl_xor(sum, 2);
    sum += __shfl_xor(sum, 4);
    ATT[t] = e / sum;
  }
  __syncthreads();

  // ---- V-GEMM: [Zc | z] @ Wv2c ----
  f32x4 vacc[4];
#pragma unroll
  for (int ct = 0; ct < 4; ++ct) {
    float bv = BV[ct * 16 + n];
#pragma unroll
    for (int r = 0; r < 4; ++r) vacc[ct][r] = bv;
  }
#pragma unroll
  for (int ks = 0; ks < 4; ++ks) {
    int c0 = ks * 32 + kg * 8;
    bf16x8 a = (ks < 2) ? ldT(VT, row0 + am, c0) : ldA_z(zK, c0 - 64);
#pragma unroll
    for (int ct = 0; ct < 4; ++ct) vacc[ct] = MFMA(a, ldB(Wv, ct * 16 + n, c0), vacc[ct]);
  }
#pragma unroll
  for (int ct = 0; ct < 4; ++ct)
#pragma unroll
    for (int r = 0; r < 4; ++r)
      KV[(row0 + kg * 4 + r) * 77 + ct * 16 + n] = vacc[ct][r];
  __syncthreads();

  // ---- attn @ V ----
  {
    int p = t >> 5, dp = t & 7, h = (t >> 3) & 3;
    int d0 = h * 16 + dp * 2;
    float o0 = 0.f, o1 = 0.f;
#pragma unroll
    for (int k = 0; k < 8; ++k) {
      float a = ATT[(t & ~7) + k];
      const float* vrow = &KV[(p * 8 + k) * 77 + d0];
      o0 += a * vrow[0];
      o1 += a * vrow[1];
    }
    AO[p * 68 + d0] = o0;
    AO[p * 68 + d0 + 1] = o1;
  }
  __syncthreads();

  // ---- out-proj -> d_out [B,E,H,W] fp32 ----
  {
    int colo = wv * 16 + n;
    f32x4 oacc;
    float bo = outb[colo];
#pragma unroll
    for (int r = 0; r < 4; ++r) oacc[r] = bo;
#pragma unroll
    for (int ks = 0; ks < 2; ++ks) {
      int c0 = ks * 32 + kg * 8;
      bf16x8 a;
#pragma unroll
      for (int j = 0; j < 8; ++j) a[j] = f2bf(AO[(am & 7) * 68 + c0 + j]);
      oacc = MFMA(a, ldB(Wo, colo, c0), oacc);
    }
#pragma unroll
    for (int r = 0; r < 4; ++r) {
      int m = kg * 4 + r;
      if (m < 8) out[((size_t)(b * 64 + colo)) * HWp + p0 + m] = oacc[r];
    }
  }
}

extern "C" void kernel_launch(void* const* d_in, const int* in_sizes, int n_in,
                              void* d_out, int out_size, void* d_ws, size_t ws_size,
                              hipStream_t stream) {
  const float* HFs = (const float*)d_in[0];
  const float* HFc = (const float*)d_in[1];
  const float* Zc = (const float*)d_in[2];
  const float* q1w = (const float*)d_in[3];  const float* q1b = (const float*)d_in[4];
  const float* k1w = (const float*)d_in[5];  const float* k1b = (const float*)d_in[6];
  const float* v1w = (const float*)d_in[7];  const float* v1b = (const float*)d_in[8];
  const float* q2w = (const float*)d_in[9];  const float* q2b = (const float*)d_in[10];
  const float* k2w = (const float*)d_in[11]; const float* k2b = (const float*)d_in[12];
  const float* v2w = (const float*)d_in[13]; const float* v2b = (const float*)d_in[14];
  const float* ipw = (const float*)d_in[15]; const float* ipb = (const float*)d_in[16];
  const float* ow = (const float*)d_in[17];  const float* ob = (const float*)d_in[18];

  short* Wt = (short*)d_ws;                          // 7 x 64 x 136 bf16 = 121856 B
  float* Bc = (float*)((char*)d_ws + 121856);        // 6 x 64 fp32
  short* zb = (short*)((char*)d_ws + 131072);        // B*HW*64 bf16 = 8.39 MB
  float* out = (float*)d_out;

  dim3 gsetup(33, 7);
  setup_weights<<<gsetup, 256, 0, stream>>>(q1w, q1b, k1w, k1b, v1w, v1b,
                                            q2w, q2b, k2w, k2b, v2w, v2b,
                                            ipw, ipb, ow, Wt, Bc);
  stage1<<<8192, 256, 0, stream>>>(HFs, HFc, Zc, Wt, Bc, ob, zb);
  stage2<<<8192, 256, 0, stream>>>(HFs, HFc, Zc, Wt, Bc, ob, zb, out);
}